// Round 1
// baseline (473.252 us; speedup 1.0000x reference)
//
#include <hip/hip_runtime.h>

#define ENT 200
#define RELD 200
#define NREL 1000
#define NBATCH 16384
#define MARGIN 4.0f
#define CHUNK 32
#define NVEC 128
#define MAXCHUNKS 1512   // >= 16384/32 + 1000 = 1512

// B-fragment LDS layout (verified R4): 16B slot index = buf*BBUF + i*BSTRIDE_I + w
//   w = writer slot (0..207) = sq*52 + sc*4 + snp, i = col&3
#define BSTRIDE_I 211
#define BBUF 844

// ---- workspace layout (int units) ----
#define WS_NCHUNKS 3072    // [4]
#define WS_CHUNKS 3076     // int4[1512] -> ints [3076, 9124)
#define WS_LIST 11268      // [16384]
#define WS_ELEM 27652      // float[16384] (byte 110608, 16B aligned)

typedef __attribute__((ext_vector_type(8))) short short8;
typedef __attribute__((ext_vector_type(4))) float floatx4;

__device__ __forceinline__ unsigned short f2bf(float x) {
    unsigned u = __float_as_uint(x);
    u = (u + 0x7FFFu + ((u >> 16) & 1u)) >> 16;   // RNE
    return (unsigned short)u;
}

__device__ __forceinline__ float wave_reduce(float v) {
#pragma unroll
    for (int off = 32; off > 0; off >>= 1) v += __shfl_down(v, off, 64);
    return v;
}

// Fused zero+count+scan+fill: one block, counters/cursors/scan entirely in LDS.
// Each thread owns 16 batch items (coalesced), builds the per-relation item
// list, chunk table (CHUNK=32 -> ~1 chunk per relation) and nchunks.
__global__ __launch_bounds__(1024) void prep_kernel(const int* __restrict__ pos_r,
                                                    int* __restrict__ ws) {
    __shared__ int cnt_s[NREL];    // counters, then reused as fill cursors
    __shared__ int off_s[NREL];
    __shared__ int scan_s[1024];
    const int tid = threadIdx.x;

    for (int i = tid; i < NREL; i += 1024) cnt_s[i] = 0;
    __syncthreads();

    int rl[16];
#pragma unroll
    for (int k = 0; k < 16; ++k) {
        rl[k] = pos_r[(k << 10) + tid];
        atomicAdd(&cnt_s[rl[k]], 1);
    }
    __syncthreads();

    const int cnt = (tid < NREL) ? cnt_s[tid] : 0;

    // inclusive scan of counts -> item offsets
    scan_s[tid] = cnt;
    __syncthreads();
#pragma unroll
    for (int off = 1; off < 1024; off <<= 1) {
        const int add = (tid >= off) ? scan_s[tid - off] : 0;
        __syncthreads();
        scan_s[tid] += add;
        __syncthreads();
    }
    const int myoff = scan_s[tid] - cnt;
    if (tid < NREL) off_s[tid] = myoff;
    __syncthreads();

    // inclusive scan of chunk counts -> chunk table bases
    const int nch = (cnt + CHUNK - 1) / CHUNK;
    scan_s[tid] = nch;
    __syncthreads();
#pragma unroll
    for (int off = 1; off < 1024; off <<= 1) {
        const int add = (tid >= off) ? scan_s[tid - off] : 0;
        __syncthreads();
        scan_s[tid] += add;
        __syncthreads();
    }
    const int cbase = scan_s[tid] - nch;
    int4* chunks = (int4*)(ws + WS_CHUNKS);
    for (int k = 0; k < nch; ++k)
        chunks[cbase + k] = make_int4(tid, myoff + CHUNK * k, min(CHUNK, cnt - CHUNK * k), 0);
    if (tid == 1023) ws[WS_NCHUNKS] = scan_s[1023];

    // fill item list via LDS cursors (reuse cnt_s)
    if (tid < NREL) cnt_s[tid] = 0;
    __syncthreads();
#pragma unroll
    for (int k = 0; k < 16; ++k) {
        const int r = rl[k];
        const int p = off_s[r] + atomicAdd(&cnt_s[r], 1);
        ws[WS_LIST + p] = (k << 10) + tid;
    }
}

// One block (512 thr = 8 waves) per chunk of <=32 items sharing one relation:
// each 160KB transfer matrix is now streamed through LDS exactly ONCE per
// iteration (CHUNK=32 >= max per-relation count w.h.p.). Waves 0-3 also stage
// B (slots 0..207, layout unchanged); waves 4-7 are pure MFMA consumers.
// XCD-contiguous swizzle kept (harmless).
__global__ __launch_bounds__(512, 6) void transr_mfma_kernel(
    const int* __restrict__ pos_h, const int* __restrict__ pos_t,
    const int* __restrict__ neg_h, const int* __restrict__ neg_t,
    const float* __restrict__ ent_emb, const float* __restrict__ rel_emb,
    const float* __restrict__ transfer, int* __restrict__ ws)
{
    const int nch = ws[WS_NCHUNKS];
    const int stride = (nch + 7) >> 3;
    const int bidx = blockIdx.x;
    if ((bidx >> 3) >= stride) return;
    const int cix = (bidx & 7) * stride + (bidx >> 3);
    if (cix >= nch) return;

    __shared__ short sB[2 * BBUF * 8];   // 27008 B double-buffered B-fragments
    __shared__ int items_s[CHUNK];
    __shared__ int rows[NVEC];

    const int4 ck = ((const int4*)(ws + WS_CHUNKS))[cix];
    const int r = ck.x, start = ck.y, cnt = ck.z;

    const int tid  = threadIdx.x;
    const int lane = tid & 63;
    const int wv   = tid >> 6;      // row-tile 0..7
    const int q    = lane >> 4;
    const int n    = lane & 15;
    const bool wactive = (wv * 4 < cnt);   // wave's items: wv*4 .. wv*4+3

    if (tid < CHUNK) items_s[tid] = ws[WS_LIST + start + min(tid, cnt - 1)];
    __syncthreads();
    if (tid < NVEC) {
        const int b = items_s[tid >> 2];
        const int c = tid & 3;
        rows[tid] = (c == 0) ? pos_h[b] : (c == 1) ? pos_t[b] : (c == 2) ? neg_h[b] : neg_t[b];
    }
    __syncthreads();

    // A fragments in registers (active waves only): lane row m=n, k = s*32+q*8+j
    short8 afrag[7];
#pragma unroll
    for (int s = 0; s < 7; ++s) afrag[s] = (short8){0, 0, 0, 0, 0, 0, 0, 0};
    if (wactive) {
        const int row = rows[wv * 16 + n];
        const float* __restrict__ ab = ent_emb + (size_t)row * ENT;
#pragma unroll
        for (int s = 0; s < 7; ++s) {
            const int e0 = s * 32 + q * 8;
            if (e0 < ENT) {
                float v[8];
                *(float4*)(&v[0]) = *(const float4*)(ab + e0);
                *(float4*)(&v[4]) = *(const float4*)(ab + e0 + 4);
                short8 f;
#pragma unroll
                for (int j = 0; j < 8; ++j) f[j] = (short)f2bf(v[j]);
                afrag[s] = f;
            }
        }
    }

    // B staging: slot=tid (0..207 active), covers 4 cols x 8 rows per slab.
    const int slot = tid;
    const int sq   = slot / 52;
    const int srem = slot - sq * 52;
    const int scol = srem * 4;
    const bool sact = (slot < 208) && (scol < RELD);
    const float* __restrict__ Mb = transfer + (size_t)r * (ENT * RELD) + scol;
    const int k0 = sq * 8;

    float fm[8][4];     // in-flight fp32 slab
    short8 bh[4];       // converted slab awaiting commit
#define LOAD_SLAB(s_)                                                          \
    {                                                                          \
        const int kk = (s_) * 32 + k0;                                         \
        if (sact && kk < ENT) {                                                \
            _Pragma("unroll")                                                  \
            for (int j = 0; j < 8; ++j)                                        \
                *(float4*)(&fm[j][0]) = *(const float4*)(Mb + (size_t)(kk + j) * RELD); \
        } else {                                                               \
            _Pragma("unroll")                                                  \
            for (int j = 0; j < 8; ++j) {                                      \
                fm[j][0] = 0.f; fm[j][1] = 0.f; fm[j][2] = 0.f; fm[j][3] = 0.f;\
            }                                                                  \
        }                                                                      \
    }
#define CONV_SLAB()                                                            \
    {                                                                          \
        _Pragma("unroll")                                                      \
        for (int i = 0; i < 4; ++i) {                                          \
            short8 f;                                                          \
            _Pragma("unroll")                                                  \
            for (int j = 0; j < 8; ++j) f[j] = (short)f2bf(fm[j][i]);          \
            bh[i] = f;                                                         \
        }                                                                      \
    }
#define WRITE_SLAB(buf_)                                                       \
    if (slot < 208) {                                                          \
        _Pragma("unroll")                                                      \
        for (int i = 0; i < 4; ++i)                                            \
            *(short8*)(&sB[((buf_) * BBUF + i * BSTRIDE_I + slot) * 8]) = bh[i]; \
    }

    floatx4 acc[13];
#pragma unroll
    for (int c = 0; c < 13; ++c) acc[c] = (floatx4){0.f, 0.f, 0.f, 0.f};

    const int rb16 = (n & 3) * BSTRIDE_I + q * 52 + (n >> 2);  // + c*4 + buf*BBUF

    // pipeline preamble: buf0 <- slab0; bh <- slab1
    LOAD_SLAB(0); CONV_SLAB(); WRITE_SLAB(0);
    LOAD_SLAB(1); CONV_SLAB();
    __syncthreads();

#pragma unroll
    for (int s = 0; s < 7; ++s) {
        if (s < 5) LOAD_SLAB(s + 2);           // loads in flight over MFMA + write
        if (wactive) {
            const int bb = (s & 1) * BBUF;
#pragma unroll
            for (int c = 0; c < 13; ++c) {
                const short8 bf = *(const short8*)(&sB[(bb + rb16 + c * 4) * 8]);
                acc[c] = __builtin_amdgcn_mfma_f32_16x16x32_bf16(afrag[s], bf, acc[c], 0, 0, 0);
            }
        }
        if (s < 6) WRITE_SLAB((s + 1) & 1);    // bh still holds slab s+1
        if (s < 5) CONV_SLAB();                // fm(s+2) -> bh, vmcnt covered by MFMA+write
        if (s < 6) __syncthreads();
    }

    // ---- in-lane epilogue (active waves only) ----
    if (wactive) {
        float rl[13];
        const float* __restrict__ rb = rel_emb + (size_t)r * RELD;
#pragma unroll
        for (int c = 0; c < 13; ++c) {
            const int col = c * 16 + n;
            rl[c] = (col < RELD) ? rb[col] : 0.f;
        }
        float nsq[4] = {0.f, 0.f, 0.f, 0.f};
        float rsq = 0.f;
#pragma unroll
        for (int c = 0; c < 13; ++c) {
            nsq[0] += acc[c][0] * acc[c][0];
            nsq[1] += acc[c][1] * acc[c][1];
            nsq[2] += acc[c][2] * acc[c][2];
            nsq[3] += acc[c][3] * acc[c][3];
            rsq += rl[c] * rl[c];
        }
#pragma unroll
        for (int m = 1; m < 16; m <<= 1) {
#pragma unroll
            for (int k = 0; k < 4; ++k) nsq[k] += __shfl_xor(nsq[k], m, 64);
            rsq += __shfl_xor(rsq, m, 64);
        }
        float inv[4];
#pragma unroll
        for (int k = 0; k < 4; ++k) inv[k] = rsqrtf(fmaxf(nsq[k], 1e-12f));
        const float invr = rsqrtf(fmaxf(rsq, 1e-12f));

        float psum = 0.f, nsum = 0.f;
#pragma unroll
        for (int c = 0; c < 13; ++c) {
            const float rr = rl[c] * invr;
            psum += fabsf(acc[c][0] * inv[0] + rr - acc[c][1] * inv[1]);
            nsum += fabsf(acc[c][2] * inv[2] + rr - acc[c][3] * inv[3]);
        }
#pragma unroll
        for (int m = 1; m < 16; m <<= 1) {
            psum += __shfl_xor(psum, m, 64);
            nsum += __shfl_xor(nsum, m, 64);
        }
        const int item = wv * 4 + q;
        if (n == 0 && item < cnt) {
            float* elem = (float*)(ws + WS_ELEM);
            elem[items_s[item]] = fmaxf(psum - nsum + MARGIN, 0.f);
        }
    }
}

__global__ __launch_bounds__(256) void reduce_mean_kernel(const int* __restrict__ ws,
                                                          float* __restrict__ out) {
    __shared__ float sred[4];
    const float4* elem = (const float4*)(ws + WS_ELEM);
    float s = 0.f;
    for (int i = threadIdx.x; i < NBATCH / 4; i += 256) {
        const float4 v = elem[i];
        s += v.x + v.y + v.z + v.w;
    }
    s = wave_reduce(s);
    const int lane = threadIdx.x & 63;
    const int wvv = threadIdx.x >> 6;
    if (lane == 0) sred[wvv] = s;
    __syncthreads();
    if (threadIdx.x == 0)
        out[0] = (sred[0] + sred[1] + sred[2] + sred[3]) * (1.0f / (float)NBATCH);
}

extern "C" void kernel_launch(void* const* d_in, const int* in_sizes, int n_in,
                              void* d_out, int out_size, void* d_ws, size_t ws_size,
                              hipStream_t stream) {
    const int* pos_h = (const int*)d_in[0];
    const int* pos_t = (const int*)d_in[1];
    const int* pos_r = (const int*)d_in[2];
    const int* neg_h = (const int*)d_in[3];
    const int* neg_t = (const int*)d_in[4];
    const float* ent_emb = (const float*)d_in[5];
    const float* rel_emb = (const float*)d_in[6];
    const float* transfer = (const float*)d_in[7];

    int* ws = (int*)d_ws;
    float* out = (float*)d_out;

    prep_kernel<<<1, 1024, 0, stream>>>(pos_r, ws);
    transr_mfma_kernel<<<MAXCHUNKS, 512, 0, stream>>>(
        pos_h, pos_t, neg_h, neg_t, ent_emb, rel_emb, transfer, ws);
    reduce_mean_kernel<<<1, 256, 0, stream>>>(ws, out);
}

// Round 2
// 349.944 us; speedup vs baseline: 1.3524x; 1.3524x over previous
//
#include <hip/hip_runtime.h>

#define ENT 200
#define RELD 200
#define NREL 1000
#define NBATCH 16384
#define MARGIN 4.0f
#define CHUNK 32
#define NVEC 128
#define MAXCHUNKS 1512   // >= 16384/32 + 1000 = 1512

// B-fragment LDS layout (verified R4): 16B slot index = buf*BBUF + i*BSTRIDE_I + w
//   w = writer slot (0..207) = sq*52 + sc*4 + snp, i = col&3
#define BSTRIDE_I 211
#define BBUF 844

// ---- workspace layout (int units) ----
#define WS_NCHUNKS 3072    // [4]
#define WS_CHUNKS 3076     // int4[1512] -> ints [3076, 9124)
#define WS_LIST 11268      // [16384]
#define WS_ELEM 27652      // float[16384] (byte 110608, 16B aligned)

typedef __attribute__((ext_vector_type(8))) short short8;
typedef __attribute__((ext_vector_type(4))) float floatx4;

__device__ __forceinline__ unsigned short f2bf(float x) {
    unsigned u = __float_as_uint(x);
    u = (u + 0x7FFFu + ((u >> 16) & 1u)) >> 16;   // RNE
    return (unsigned short)u;
}

__device__ __forceinline__ float wave_reduce(float v) {
#pragma unroll
    for (int off = 32; off > 0; off >>= 1) v += __shfl_down(v, off, 64);
    return v;
}

// Fused zero+count+scan+fill: one block, counters/cursors/scan entirely in LDS.
__global__ __launch_bounds__(1024) void prep_kernel(const int* __restrict__ pos_r,
                                                    int* __restrict__ ws) {
    __shared__ int cnt_s[NREL];    // counters, then reused as fill cursors
    __shared__ int off_s[NREL];
    __shared__ int scan_s[1024];
    const int tid = threadIdx.x;

    for (int i = tid; i < NREL; i += 1024) cnt_s[i] = 0;
    __syncthreads();

    int rl[16];
#pragma unroll
    for (int k = 0; k < 16; ++k) {
        rl[k] = pos_r[(k << 10) + tid];
        atomicAdd(&cnt_s[rl[k]], 1);
    }
    __syncthreads();

    const int cnt = (tid < NREL) ? cnt_s[tid] : 0;

    // inclusive scan of counts -> item offsets
    scan_s[tid] = cnt;
    __syncthreads();
#pragma unroll
    for (int off = 1; off < 1024; off <<= 1) {
        const int add = (tid >= off) ? scan_s[tid - off] : 0;
        __syncthreads();
        scan_s[tid] += add;
        __syncthreads();
    }
    const int myoff = scan_s[tid] - cnt;
    if (tid < NREL) off_s[tid] = myoff;
    __syncthreads();

    // inclusive scan of chunk counts -> chunk table bases
    const int nch = (cnt + CHUNK - 1) / CHUNK;
    scan_s[tid] = nch;
    __syncthreads();
#pragma unroll
    for (int off = 1; off < 1024; off <<= 1) {
        const int add = (tid >= off) ? scan_s[tid - off] : 0;
        __syncthreads();
        scan_s[tid] += add;
        __syncthreads();
    }
    const int cbase = scan_s[tid] - nch;
    int4* chunks = (int4*)(ws + WS_CHUNKS);
    for (int k = 0; k < nch; ++k)
        chunks[cbase + k] = make_int4(tid, myoff + CHUNK * k, min(CHUNK, cnt - CHUNK * k), 0);
    if (tid == 1023) ws[WS_NCHUNKS] = scan_s[1023];

    // fill item list via LDS cursors (reuse cnt_s)
    if (tid < NREL) cnt_s[tid] = 0;
    __syncthreads();
#pragma unroll
    for (int k = 0; k < 16; ++k) {
        const int r = rl[k];
        const int p = off_s[r] + atomicAdd(&cnt_s[r], 1);
        ws[WS_LIST + p] = (k << 10) + tid;
    }
}

// One block (512 thr = 8 waves) per chunk of <=32 items sharing one relation:
// each 160KB transfer matrix streamed through LDS exactly ONCE per iteration.
// Waves 0-3 stage B (slots 0..207); waves 4-7 are pure MFMA consumers.
// __launch_bounds__(512,4): VGPR cap 128 — per-thread live state is ~84 VGPRs
// (acc 52 + afrag 28 + slabs); R1's (512,6) cap of ~85 forced a 40-VGPR
// allocation with scratch spill (WRITE_SIZE 0.4->508 MB). Do NOT lower.
__global__ __launch_bounds__(512, 4) void transr_mfma_kernel(
    const int* __restrict__ pos_h, const int* __restrict__ pos_t,
    const int* __restrict__ neg_h, const int* __restrict__ neg_t,
    const float* __restrict__ ent_emb, const float* __restrict__ rel_emb,
    const float* __restrict__ transfer, int* __restrict__ ws)
{
    const int nch = ws[WS_NCHUNKS];
    const int stride = (nch + 7) >> 3;
    const int bidx = blockIdx.x;
    if ((bidx >> 3) >= stride) return;
    const int cix = (bidx & 7) * stride + (bidx >> 3);
    if (cix >= nch) return;

    __shared__ short sB[2 * BBUF * 8];   // 27008 B double-buffered B-fragments
    __shared__ int items_s[CHUNK];
    __shared__ int rows[NVEC];

    const int4 ck = ((const int4*)(ws + WS_CHUNKS))[cix];
    const int r = ck.x, start = ck.y, cnt = ck.z;

    const int tid  = threadIdx.x;
    const int lane = tid & 63;
    const int wv   = tid >> 6;      // row-tile 0..7
    const int q    = lane >> 4;
    const int n    = lane & 15;
    const bool wactive = (wv * 4 < cnt);   // wave's items: wv*4 .. wv*4+3

    if (tid < CHUNK) items_s[tid] = ws[WS_LIST + start + min(tid, cnt - 1)];
    __syncthreads();
    if (tid < NVEC) {
        const int b = items_s[tid >> 2];
        const int c = tid & 3;
        rows[tid] = (c == 0) ? pos_h[b] : (c == 1) ? pos_t[b] : (c == 2) ? neg_h[b] : neg_t[b];
    }
    __syncthreads();

    // A fragments in registers (active waves only): lane row m=n, k = s*32+q*8+j
    short8 afrag[7];
#pragma unroll
    for (int s = 0; s < 7; ++s) afrag[s] = (short8){0, 0, 0, 0, 0, 0, 0, 0};
    if (wactive) {
        const int row = rows[wv * 16 + n];
        const float* __restrict__ ab = ent_emb + (size_t)row * ENT;
#pragma unroll
        for (int s = 0; s < 7; ++s) {
            const int e0 = s * 32 + q * 8;
            if (e0 < ENT) {
                float v[8];
                *(float4*)(&v[0]) = *(const float4*)(ab + e0);
                *(float4*)(&v[4]) = *(const float4*)(ab + e0 + 4);
                short8 f;
#pragma unroll
                for (int j = 0; j < 8; ++j) f[j] = (short)f2bf(v[j]);
                afrag[s] = f;
            }
        }
    }

    // B staging: slot=tid (0..207 active), covers 4 cols x 8 rows per slab.
    const int slot = tid;
    const int sq   = slot / 52;
    const int srem = slot - sq * 52;
    const int scol = srem * 4;
    const bool sact = (slot < 208) && (scol < RELD);
    const float* __restrict__ Mb = transfer + (size_t)r * (ENT * RELD) + scol;
    const int k0 = sq * 8;

    float fm[8][4];     // in-flight fp32 slab
    short8 bh[4];       // converted slab awaiting commit
#define LOAD_SLAB(s_)                                                          \
    {                                                                          \
        const int kk = (s_) * 32 + k0;                                         \
        if (sact && kk < ENT) {                                                \
            _Pragma("unroll")                                                  \
            for (int j = 0; j < 8; ++j)                                        \
                *(float4*)(&fm[j][0]) = *(const float4*)(Mb + (size_t)(kk + j) * RELD); \
        } else {                                                               \
            _Pragma("unroll")                                                  \
            for (int j = 0; j < 8; ++j) {                                      \
                fm[j][0] = 0.f; fm[j][1] = 0.f; fm[j][2] = 0.f; fm[j][3] = 0.f;\
            }                                                                  \
        }                                                                      \
    }
#define CONV_SLAB()                                                            \
    {                                                                          \
        _Pragma("unroll")                                                      \
        for (int i = 0; i < 4; ++i) {                                          \
            short8 f;                                                          \
            _Pragma("unroll")                                                  \
            for (int j = 0; j < 8; ++j) f[j] = (short)f2bf(fm[j][i]);          \
            bh[i] = f;                                                         \
        }                                                                      \
    }
#define WRITE_SLAB(buf_)                                                       \
    if (slot < 208) {                                                          \
        _Pragma("unroll")                                                      \
        for (int i = 0; i < 4; ++i)                                            \
            *(short8*)(&sB[((buf_) * BBUF + i * BSTRIDE_I + slot) * 8]) = bh[i]; \
    }

    floatx4 acc[13];
#pragma unroll
    for (int c = 0; c < 13; ++c) acc[c] = (floatx4){0.f, 0.f, 0.f, 0.f};

    const int rb16 = (n & 3) * BSTRIDE_I + q * 52 + (n >> 2);  // + c*4 + buf*BBUF

    // pipeline preamble: buf0 <- slab0; bh <- slab1
    LOAD_SLAB(0); CONV_SLAB(); WRITE_SLAB(0);
    LOAD_SLAB(1); CONV_SLAB();
    __syncthreads();

#pragma unroll
    for (int s = 0; s < 7; ++s) {
        if (s < 5) LOAD_SLAB(s + 2);           // loads in flight over MFMA + write
        if (wactive) {
            const int bb = (s & 1) * BBUF;
#pragma unroll
            for (int c = 0; c < 13; ++c) {
                const short8 bf = *(const short8*)(&sB[(bb + rb16 + c * 4) * 8]);
                acc[c] = __builtin_amdgcn_mfma_f32_16x16x32_bf16(afrag[s], bf, acc[c], 0, 0, 0);
            }
        }
        if (s < 6) WRITE_SLAB((s + 1) & 1);    // bh still holds slab s+1
        if (s < 5) CONV_SLAB();                // fm(s+2) -> bh, vmcnt covered by MFMA+write
        if (s < 6) __syncthreads();
    }

    // ---- in-lane epilogue (active waves only) ----
    if (wactive) {
        float rl[13];
        const float* __restrict__ rb = rel_emb + (size_t)r * RELD;
#pragma unroll
        for (int c = 0; c < 13; ++c) {
            const int col = c * 16 + n;
            rl[c] = (col < RELD) ? rb[col] : 0.f;
        }
        float nsq[4] = {0.f, 0.f, 0.f, 0.f};
        float rsq = 0.f;
#pragma unroll
        for (int c = 0; c < 13; ++c) {
            nsq[0] += acc[c][0] * acc[c][0];
            nsq[1] += acc[c][1] * acc[c][1];
            nsq[2] += acc[c][2] * acc[c][2];
            nsq[3] += acc[c][3] * acc[c][3];
            rsq += rl[c] * rl[c];
        }
#pragma unroll
        for (int m = 1; m < 16; m <<= 1) {
#pragma unroll
            for (int k = 0; k < 4; ++k) nsq[k] += __shfl_xor(nsq[k], m, 64);
            rsq += __shfl_xor(rsq, m, 64);
        }
        float inv[4];
#pragma unroll
        for (int k = 0; k < 4; ++k) inv[k] = rsqrtf(fmaxf(nsq[k], 1e-12f));
        const float invr = rsqrtf(fmaxf(rsq, 1e-12f));

        float psum = 0.f, nsum = 0.f;
#pragma unroll
        for (int c = 0; c < 13; ++c) {
            const float rr = rl[c] * invr;
            psum += fabsf(acc[c][0] * inv[0] + rr - acc[c][1] * inv[1]);
            nsum += fabsf(acc[c][2] * inv[2] + rr - acc[c][3] * inv[3]);
        }
#pragma unroll
        for (int m = 1; m < 16; m <<= 1) {
            psum += __shfl_xor(psum, m, 64);
            nsum += __shfl_xor(nsum, m, 64);
        }
        const int item = wv * 4 + q;
        if (n == 0 && item < cnt) {
            float* elem = (float*)(ws + WS_ELEM);
            elem[items_s[item]] = fmaxf(psum - nsum + MARGIN, 0.f);
        }
    }
}

__global__ __launch_bounds__(256) void reduce_mean_kernel(const int* __restrict__ ws,
                                                          float* __restrict__ out) {
    __shared__ float sred[4];
    const float4* elem = (const float4*)(ws + WS_ELEM);
    float s = 0.f;
    for (int i = threadIdx.x; i < NBATCH / 4; i += 256) {
        const float4 v = elem[i];
        s += v.x + v.y + v.z + v.w;
    }
    s = wave_reduce(s);
    const int lane = threadIdx.x & 63;
    const int wvv = threadIdx.x >> 6;
    if (lane == 0) sred[wvv] = s;
    __syncthreads();
    if (threadIdx.x == 0)
        out[0] = (sred[0] + sred[1] + sred[2] + sred[3]) * (1.0f / (float)NBATCH);
}

extern "C" void kernel_launch(void* const* d_in, const int* in_sizes, int n_in,
                              void* d_out, int out_size, void* d_ws, size_t ws_size,
                              hipStream_t stream) {
    const int* pos_h = (const int*)d_in[0];
    const int* pos_t = (const int*)d_in[1];
    const int* pos_r = (const int*)d_in[2];
    const int* neg_h = (const int*)d_in[3];
    const int* neg_t = (const int*)d_in[4];
    const float* ent_emb = (const float*)d_in[5];
    const float* rel_emb = (const float*)d_in[6];
    const float* transfer = (const float*)d_in[7];

    int* ws = (int*)d_ws;
    float* out = (float*)d_out;

    prep_kernel<<<1, 1024, 0, stream>>>(pos_r, ws);
    transr_mfma_kernel<<<MAXCHUNKS, 512, 0, stream>>>(
        pos_h, pos_t, neg_h, neg_t, ent_emb, rel_emb, transfer, ws);
    reduce_mean_kernel<<<1, 256, 0, stream>>>(ws, out);
}

// Round 3
// 319.321 us; speedup vs baseline: 1.4821x; 1.0959x over previous
//
#include <hip/hip_runtime.h>

#define ENT 200
#define RELD 200
#define NREL 1000
#define NBATCH 16384
#define MARGIN 4.0f
#define CHUNK 32
#define NVEC 128
#define MAXCHUNKS 1512   // >= 16384/32 + 1000 = 1512

// B-fragment LDS layout (verified R4): 16B slot index = buf*BBUF + i*BSTRIDE_I + w
//   w = writer slot (0..207) = sq*52 + sc*4 + snp, i = col&3
#define BSTRIDE_I 211
#define BBUF 844

// ---- workspace layout (int units) ----
#define WS_NCHUNKS 3072    // [4]
#define WS_CHUNKS 3076     // int4[1512] -> ints [3076, 9124)
#define WS_LIST 11268      // [16384]
#define WS_ELEM 27652      // float[16384] (byte 110608, 16B aligned)

typedef __attribute__((ext_vector_type(8))) short short8;
typedef __attribute__((ext_vector_type(4))) float floatx4;

__device__ __forceinline__ unsigned short f2bf(float x) {
    unsigned u = __float_as_uint(x);
    u = (u + 0x7FFFu + ((u >> 16) & 1u)) >> 16;   // RNE
    return (unsigned short)u;
}

__device__ __forceinline__ float wave_reduce(float v) {
#pragma unroll
    for (int off = 32; off > 0; off >>= 1) v += __shfl_down(v, off, 64);
    return v;
}

// Fused zero+count+scan+fill: one block, counters/cursors/scan entirely in LDS.
__global__ __launch_bounds__(1024) void prep_kernel(const int* __restrict__ pos_r,
                                                    int* __restrict__ ws) {
    __shared__ int cnt_s[NREL];    // counters, then reused as fill cursors
    __shared__ int off_s[NREL];
    __shared__ int scan_s[1024];
    const int tid = threadIdx.x;

    for (int i = tid; i < NREL; i += 1024) cnt_s[i] = 0;
    __syncthreads();

    int rl[16];
#pragma unroll
    for (int k = 0; k < 16; ++k) {
        rl[k] = pos_r[(k << 10) + tid];
        atomicAdd(&cnt_s[rl[k]], 1);
    }
    __syncthreads();

    const int cnt = (tid < NREL) ? cnt_s[tid] : 0;

    // inclusive scan of counts -> item offsets
    scan_s[tid] = cnt;
    __syncthreads();
#pragma unroll
    for (int off = 1; off < 1024; off <<= 1) {
        const int add = (tid >= off) ? scan_s[tid - off] : 0;
        __syncthreads();
        scan_s[tid] += add;
        __syncthreads();
    }
    const int myoff = scan_s[tid] - cnt;
    if (tid < NREL) off_s[tid] = myoff;
    __syncthreads();

    // inclusive scan of chunk counts -> chunk table bases
    const int nch = (cnt + CHUNK - 1) / CHUNK;
    scan_s[tid] = nch;
    __syncthreads();
#pragma unroll
    for (int off = 1; off < 1024; off <<= 1) {
        const int add = (tid >= off) ? scan_s[tid - off] : 0;
        __syncthreads();
        scan_s[tid] += add;
        __syncthreads();
    }
    const int cbase = scan_s[tid] - nch;
    int4* chunks = (int4*)(ws + WS_CHUNKS);
    for (int k = 0; k < nch; ++k)
        chunks[cbase + k] = make_int4(tid, myoff + CHUNK * k, min(CHUNK, cnt - CHUNK * k), 0);
    if (tid == 1023) ws[WS_NCHUNKS] = scan_s[1023];

    // fill item list via LDS cursors (reuse cnt_s)
    if (tid < NREL) cnt_s[tid] = 0;
    __syncthreads();
#pragma unroll
    for (int k = 0; k < 16; ++k) {
        const int r = rl[k];
        const int p = off_s[r] + atomicAdd(&cnt_s[r], 1);
        ws[WS_LIST + p] = (k << 10) + tid;
    }
}

// One block (512 thr = 8 waves) per chunk of <=32 items sharing one relation:
// each 160KB transfer matrix streamed through LDS exactly ONCE per iteration.
// Waves 0-3 stage B (slots 0..207); waves 4-7 are pure MFMA consumers.
//
// REGISTER BUDGET (gfx950 UNIFIED VGPR+AGPR file): per-thread live state is
// ~84 arch-VGPRs + ~64 AGPRs (acc[13] floatx4) ~= 148 total. Any min-waves
// clause that caps below that spills to scratch:
//   R1 (512,6) cap~85  -> 40 VGPR, WRITE_SIZE 508 MB, 265 us
//   R2 (512,4) cap 128 -> 64 VGPR, WRITE_SIZE 125 MB, 130 us
// So: NO min-waves clause. Occupancy (~2 blocks/CU) is fine; kernel is
// traffic-bound, not occupancy-bound.
__global__ __launch_bounds__(512) void transr_mfma_kernel(
    const int* __restrict__ pos_h, const int* __restrict__ pos_t,
    const int* __restrict__ neg_h, const int* __restrict__ neg_t,
    const float* __restrict__ ent_emb, const float* __restrict__ rel_emb,
    const float* __restrict__ transfer, int* __restrict__ ws)
{
    const int nch = ws[WS_NCHUNKS];
    const int stride = (nch + 7) >> 3;
    const int bidx = blockIdx.x;
    if ((bidx >> 3) >= stride) return;
    const int cix = (bidx & 7) * stride + (bidx >> 3);
    if (cix >= nch) return;

    __shared__ short sB[2 * BBUF * 8];   // 27008 B double-buffered B-fragments
    __shared__ int items_s[CHUNK];
    __shared__ int rows[NVEC];

    const int4 ck = ((const int4*)(ws + WS_CHUNKS))[cix];
    const int r = ck.x, start = ck.y, cnt = ck.z;

    const int tid  = threadIdx.x;
    const int lane = tid & 63;
    const int wv   = tid >> 6;      // row-tile 0..7
    const int q    = lane >> 4;
    const int n    = lane & 15;
    const bool wactive = (wv * 4 < cnt);   // wave's items: wv*4 .. wv*4+3

    if (tid < CHUNK) items_s[tid] = ws[WS_LIST + start + min(tid, cnt - 1)];
    __syncthreads();
    if (tid < NVEC) {
        const int b = items_s[tid >> 2];
        const int c = tid & 3;
        rows[tid] = (c == 0) ? pos_h[b] : (c == 1) ? pos_t[b] : (c == 2) ? neg_h[b] : neg_t[b];
    }
    __syncthreads();

    // A fragments in registers (active waves only): lane row m=n, k = s*32+q*8+j
    short8 afrag[7];
#pragma unroll
    for (int s = 0; s < 7; ++s) afrag[s] = (short8){0, 0, 0, 0, 0, 0, 0, 0};
    if (wactive) {
        const int row = rows[wv * 16 + n];
        const float* __restrict__ ab = ent_emb + (size_t)row * ENT;
#pragma unroll
        for (int s = 0; s < 7; ++s) {
            const int e0 = s * 32 + q * 8;
            if (e0 < ENT) {
                float v[8];
                *(float4*)(&v[0]) = *(const float4*)(ab + e0);
                *(float4*)(&v[4]) = *(const float4*)(ab + e0 + 4);
                short8 f;
#pragma unroll
                for (int j = 0; j < 8; ++j) f[j] = (short)f2bf(v[j]);
                afrag[s] = f;
            }
        }
    }

    // B staging: slot=tid (0..207 active), covers 4 cols x 8 rows per slab.
    const int slot = tid;
    const int sq   = slot / 52;
    const int srem = slot - sq * 52;
    const int scol = srem * 4;
    const bool sact = (slot < 208) && (scol < RELD);
    const float* __restrict__ Mb = transfer + (size_t)r * (ENT * RELD) + scol;
    const int k0 = sq * 8;

    float fm[8][4];     // in-flight fp32 slab
    short8 bh[4];       // converted slab awaiting commit
#define LOAD_SLAB(s_)                                                          \
    {                                                                          \
        const int kk = (s_) * 32 + k0;                                         \
        if (sact && kk < ENT) {                                                \
            _Pragma("unroll")                                                  \
            for (int j = 0; j < 8; ++j)                                        \
                *(float4*)(&fm[j][0]) = *(const float4*)(Mb + (size_t)(kk + j) * RELD); \
        } else {                                                               \
            _Pragma("unroll")                                                  \
            for (int j = 0; j < 8; ++j) {                                      \
                fm[j][0] = 0.f; fm[j][1] = 0.f; fm[j][2] = 0.f; fm[j][3] = 0.f;\
            }                                                                  \
        }                                                                      \
    }
#define CONV_SLAB()                                                            \
    {                                                                          \
        _Pragma("unroll")                                                      \
        for (int i = 0; i < 4; ++i) {                                          \
            short8 f;                                                          \
            _Pragma("unroll")                                                  \
            for (int j = 0; j < 8; ++j) f[j] = (short)f2bf(fm[j][i]);          \
            bh[i] = f;                                                         \
        }                                                                      \
    }
#define WRITE_SLAB(buf_)                                                       \
    if (slot < 208) {                                                          \
        _Pragma("unroll")                                                      \
        for (int i = 0; i < 4; ++i)                                            \
            *(short8*)(&sB[((buf_) * BBUF + i * BSTRIDE_I + slot) * 8]) = bh[i]; \
    }

    floatx4 acc[13];
#pragma unroll
    for (int c = 0; c < 13; ++c) acc[c] = (floatx4){0.f, 0.f, 0.f, 0.f};

    const int rb16 = (n & 3) * BSTRIDE_I + q * 52 + (n >> 2);  // + c*4 + buf*BBUF

    // pipeline preamble: buf0 <- slab0; bh <- slab1
    LOAD_SLAB(0); CONV_SLAB(); WRITE_SLAB(0);
    LOAD_SLAB(1); CONV_SLAB();
    __syncthreads();

#pragma unroll
    for (int s = 0; s < 7; ++s) {
        if (s < 5) LOAD_SLAB(s + 2);           // loads in flight over MFMA + write
        if (wactive) {
            const int bb = (s & 1) * BBUF;
#pragma unroll
            for (int c = 0; c < 13; ++c) {
                const short8 bf = *(const short8*)(&sB[(bb + rb16 + c * 4) * 8]);
                acc[c] = __builtin_amdgcn_mfma_f32_16x16x32_bf16(afrag[s], bf, acc[c], 0, 0, 0);
            }
        }
        if (s < 6) WRITE_SLAB((s + 1) & 1);    // bh still holds slab s+1
        if (s < 5) CONV_SLAB();                // fm(s+2) -> bh, vmcnt covered by MFMA+write
        if (s < 6) __syncthreads();
    }

    // ---- in-lane epilogue (active waves only) ----
    if (wactive) {
        float rl[13];
        const float* __restrict__ rb = rel_emb + (size_t)r * RELD;
#pragma unroll
        for (int c = 0; c < 13; ++c) {
            const int col = c * 16 + n;
            rl[c] = (col < RELD) ? rb[col] : 0.f;
        }
        float nsq[4] = {0.f, 0.f, 0.f, 0.f};
        float rsq = 0.f;
#pragma unroll
        for (int c = 0; c < 13; ++c) {
            nsq[0] += acc[c][0] * acc[c][0];
            nsq[1] += acc[c][1] * acc[c][1];
            nsq[2] += acc[c][2] * acc[c][2];
            nsq[3] += acc[c][3] * acc[c][3];
            rsq += rl[c] * rl[c];
        }
#pragma unroll
        for (int m = 1; m < 16; m <<= 1) {
#pragma unroll
            for (int k = 0; k < 4; ++k) nsq[k] += __shfl_xor(nsq[k], m, 64);
            rsq += __shfl_xor(rsq, m, 64);
        }
        float inv[4];
#pragma unroll
        for (int k = 0; k < 4; ++k) inv[k] = rsqrtf(fmaxf(nsq[k], 1e-12f));
        const float invr = rsqrtf(fmaxf(rsq, 1e-12f));

        float psum = 0.f, nsum = 0.f;
#pragma unroll
        for (int c = 0; c < 13; ++c) {
            const float rr = rl[c] * invr;
            psum += fabsf(acc[c][0] * inv[0] + rr - acc[c][1] * inv[1]);
            nsum += fabsf(acc[c][2] * inv[2] + rr - acc[c][3] * inv[3]);
        }
#pragma unroll
        for (int m = 1; m < 16; m <<= 1) {
            psum += __shfl_xor(psum, m, 64);
            nsum += __shfl_xor(nsum, m, 64);
        }
        const int item = wv * 4 + q;
        if (n == 0 && item < cnt) {
            float* elem = (float*)(ws + WS_ELEM);
            elem[items_s[item]] = fmaxf(psum - nsum + MARGIN, 0.f);
        }
    }
}

__global__ __launch_bounds__(256) void reduce_mean_kernel(const int* __restrict__ ws,
                                                          float* __restrict__ out) {
    __shared__ float sred[4];
    const float4* elem = (const float4*)(ws + WS_ELEM);
    float s = 0.f;
    for (int i = threadIdx.x; i < NBATCH / 4; i += 256) {
        const float4 v = elem[i];
        s += v.x + v.y + v.z + v.w;
    }
    s = wave_reduce(s);
    const int lane = threadIdx.x & 63;
    const int wvv = threadIdx.x >> 6;
    if (lane == 0) sred[wvv] = s;
    __syncthreads();
    if (threadIdx.x == 0)
        out[0] = (sred[0] + sred[1] + sred[2] + sred[3]) * (1.0f / (float)NBATCH);
}

extern "C" void kernel_launch(void* const* d_in, const int* in_sizes, int n_in,
                              void* d_out, int out_size, void* d_ws, size_t ws_size,
                              hipStream_t stream) {
    const int* pos_h = (const int*)d_in[0];
    const int* pos_t = (const int*)d_in[1];
    const int* pos_r = (const int*)d_in[2];
    const int* neg_h = (const int*)d_in[3];
    const int* neg_t = (const int*)d_in[4];
    const float* ent_emb = (const float*)d_in[5];
    const float* rel_emb = (const float*)d_in[6];
    const float* transfer = (const float*)d_in[7];

    int* ws = (int*)d_ws;
    float* out = (float*)d_out;

    prep_kernel<<<1, 1024, 0, stream>>>(pos_r, ws);
    transr_mfma_kernel<<<MAXCHUNKS, 512, 0, stream>>>(
        pos_h, pos_t, neg_h, neg_t, ent_emb, rel_emb, transfer, ws);
    reduce_mean_kernel<<<1, 256, 0, stream>>>(ws, out);
}

// Round 4
// 319.241 us; speedup vs baseline: 1.4824x; 1.0003x over previous
//
#include <hip/hip_runtime.h>

#define ENT 200
#define RELD 200
#define NREL 1000
#define NBATCH 16384
#define MARGIN 4.0f
#define CHUNK 32
#define NVEC 128
#define MAXCHUNKS 1512   // >= 16384/32 + 1000 = 1512

// B-fragment LDS layout (generalized from verified R4 layout, now 64 rows/phase):
//   writer slot w = sq*52 + (scol/4), sq = slot/52 in 0..7 (k0 = sq*8), 416 slots
//   16B slot index = buf*BBUF + i*BSTRIDE_I + w, i = col&3
//   consumer fragment (ks,q,n,c): w = (ks*4+q)*52 + c*4 + (n>>2), i = n&3
//   BSTRIDE_I = 419 (>=416, ==3 mod 8: same bank spread as verified 211)
#define NSLOT 416
#define BSTRIDE_I 419
#define BBUF 1676        // 4*BSTRIDE_I

// ---- workspace layout (int units) ----
#define WS_NCHUNKS 3072    // [4]
#define WS_CHUNKS 3076     // int4[1512] -> ints [3076, 9124)
#define WS_LIST 11268      // [16384]
#define WS_ELEM 27652      // float[16384] (byte 110608, 16B aligned)

typedef __attribute__((ext_vector_type(8))) short short8;
typedef __attribute__((ext_vector_type(4))) float floatx4;

__device__ __forceinline__ unsigned short f2bf(float x) {
    unsigned u = __float_as_uint(x);
    u = (u + 0x7FFFu + ((u >> 16) & 1u)) >> 16;   // RNE
    return (unsigned short)u;
}

__device__ __forceinline__ float wave_reduce(float v) {
#pragma unroll
    for (int off = 32; off > 0; off >>= 1) v += __shfl_down(v, off, 64);
    return v;
}

// Fused zero+count+scan+fill: one block, counters/cursors/scan entirely in LDS.
__global__ __launch_bounds__(1024) void prep_kernel(const int* __restrict__ pos_r,
                                                    int* __restrict__ ws) {
    __shared__ int cnt_s[NREL];    // counters, then reused as fill cursors
    __shared__ int off_s[NREL];
    __shared__ int scan_s[1024];
    const int tid = threadIdx.x;

    for (int i = tid; i < NREL; i += 1024) cnt_s[i] = 0;
    __syncthreads();

    int rl[16];
#pragma unroll
    for (int k = 0; k < 16; ++k) {
        rl[k] = pos_r[(k << 10) + tid];
        atomicAdd(&cnt_s[rl[k]], 1);
    }
    __syncthreads();

    const int cnt = (tid < NREL) ? cnt_s[tid] : 0;

    // inclusive scan of counts -> item offsets
    scan_s[tid] = cnt;
    __syncthreads();
#pragma unroll
    for (int off = 1; off < 1024; off <<= 1) {
        const int add = (tid >= off) ? scan_s[tid - off] : 0;
        __syncthreads();
        scan_s[tid] += add;
        __syncthreads();
    }
    const int myoff = scan_s[tid] - cnt;
    if (tid < NREL) off_s[tid] = myoff;
    __syncthreads();

    // inclusive scan of chunk counts -> chunk table bases
    const int nch = (cnt + CHUNK - 1) / CHUNK;
    scan_s[tid] = nch;
    __syncthreads();
#pragma unroll
    for (int off = 1; off < 1024; off <<= 1) {
        const int add = (tid >= off) ? scan_s[tid - off] : 0;
        __syncthreads();
        scan_s[tid] += add;
        __syncthreads();
    }
    const int cbase = scan_s[tid] - nch;
    int4* chunks = (int4*)(ws + WS_CHUNKS);
    for (int k = 0; k < nch; ++k)
        chunks[cbase + k] = make_int4(tid, myoff + CHUNK * k, min(CHUNK, cnt - CHUNK * k), 0);
    if (tid == 1023) ws[WS_NCHUNKS] = scan_s[1023];

    // fill item list via LDS cursors (reuse cnt_s)
    if (tid < NREL) cnt_s[tid] = 0;
    __syncthreads();
#pragma unroll
    for (int k = 0; k < 16; ++k) {
        const int r = rl[k];
        const int p = off_s[r] + atomicAdd(&cnt_s[r], 1);
        ws[WS_LIST + p] = (k << 10) + tid;
    }
}

// One block (512 thr = 8 waves) per chunk of <=32 items of one relation.
// R4 restructure: 64 rows staged per phase by 416 threads (waves 0-6), so the
// barrier-gated phase count drops 7 -> 4 (R3 was ~85% latency-stall: per-phase
// loads were consumed ~200cy after issue with a vmcnt(0)+barrier drain every
// 32 rows). Per-thread staging work per phase is unchanged (8 float4 loads,
// fm stays 32 VGPR).
//
// REGISTER BUDGET (gfx950 UNIFIED VGPR+AGPR file): ~80 arch + 64 acc AGPR.
// Min-waves clauses spill to scratch (R1: 508 MB, R2: 125 MB of WRITE_SIZE).
// Keep __launch_bounds__(512) with NO min-waves clause.
__global__ __launch_bounds__(512) void transr_mfma_kernel(
    const int* __restrict__ pos_h, const int* __restrict__ pos_t,
    const int* __restrict__ neg_h, const int* __restrict__ neg_t,
    const float* __restrict__ ent_emb, const float* __restrict__ rel_emb,
    const float* __restrict__ transfer, int* __restrict__ ws)
{
    const int nch = ws[WS_NCHUNKS];
    const int stride = (nch + 7) >> 3;
    const int bidx = blockIdx.x;
    if ((bidx >> 3) >= stride) return;
    const int cix = (bidx & 7) * stride + (bidx >> 3);
    if (cix >= nch) return;

    __shared__ short sB[2 * BBUF * 8];   // 53632 B double-buffered B-fragments (64 rows each)
    __shared__ int items_s[CHUNK];
    __shared__ int rows[NVEC];

    const int4 ck = ((const int4*)(ws + WS_CHUNKS))[cix];
    const int r = ck.x, start = ck.y, cnt = ck.z;

    const int tid  = threadIdx.x;
    const int lane = tid & 63;
    const int wv   = tid >> 6;      // row-tile 0..7
    const int q    = lane >> 4;
    const int n    = lane & 15;
    const bool wactive = (wv * 4 < cnt);   // wave's items: wv*4 .. wv*4+3

    if (tid < CHUNK) items_s[tid] = ws[WS_LIST + start + min(tid, cnt - 1)];
    __syncthreads();
    if (tid < NVEC) {
        const int b = items_s[tid >> 2];
        const int c = tid & 3;
        rows[tid] = (c == 0) ? pos_h[b] : (c == 1) ? pos_t[b] : (c == 2) ? neg_h[b] : neg_t[b];
    }
    __syncthreads();

    // A fragments in registers (active waves only): lane row m=n, k = s*32+q*8+j
    short8 afrag[7];
#pragma unroll
    for (int s = 0; s < 7; ++s) afrag[s] = (short8){0, 0, 0, 0, 0, 0, 0, 0};
    if (wactive) {
        const int row = rows[wv * 16 + n];
        const float* __restrict__ ab = ent_emb + (size_t)row * ENT;
#pragma unroll
        for (int s = 0; s < 7; ++s) {
            const int e0 = s * 32 + q * 8;
            if (e0 < ENT) {
                float v[8];
                *(float4*)(&v[0]) = *(const float4*)(ab + e0);
                *(float4*)(&v[4]) = *(const float4*)(ab + e0 + 4);
                short8 f;
#pragma unroll
                for (int j = 0; j < 8; ++j) f[j] = (short)f2bf(v[j]);
                afrag[s] = f;
            }
        }
    }

    // B staging: slot=tid (0..415 active), covers 4 cols x 8 rows per phase.
    // Phase p stages rows p*64 .. p*64+63: k0 = sq*8, sq = slot/52 in 0..7.
    const int slot = tid;
    const int sq   = slot / 52;
    const int srem = slot - sq * 52;
    const int scol = srem * 4;
    const bool sact = (slot < NSLOT) && (scol < RELD);
    const float* __restrict__ Mb = transfer + (size_t)r * (ENT * RELD) + scol;
    const int k0 = sq * 8;

    float fm[8][4];     // in-flight fp32 slab
    short8 bh[4];       // converted slab awaiting commit
#define LOAD_SLAB(p_)                                                          \
    {                                                                          \
        const int kk = (p_) * 64 + k0;                                         \
        if (sact && kk < ENT) {                                                \
            _Pragma("unroll")                                                  \
            for (int j = 0; j < 8; ++j)                                        \
                *(float4*)(&fm[j][0]) = *(const float4*)(Mb + (size_t)(kk + j) * RELD); \
        } else {                                                               \
            _Pragma("unroll")                                                  \
            for (int j = 0; j < 8; ++j) {                                      \
                fm[j][0] = 0.f; fm[j][1] = 0.f; fm[j][2] = 0.f; fm[j][3] = 0.f;\
            }                                                                  \
        }                                                                      \
    }
#define CONV_SLAB()                                                            \
    {                                                                          \
        _Pragma("unroll")                                                      \
        for (int i = 0; i < 4; ++i) {                                          \
            short8 f;                                                          \
            _Pragma("unroll")                                                  \
            for (int j = 0; j < 8; ++j) f[j] = (short)f2bf(fm[j][i]);          \
            bh[i] = f;                                                         \
        }                                                                      \
    }
#define WRITE_SLAB(buf_)                                                       \
    if (slot < NSLOT) {                                                        \
        _Pragma("unroll")                                                      \
        for (int i = 0; i < 4; ++i)                                            \
            *(short8*)(&sB[((buf_) * BBUF + i * BSTRIDE_I + slot) * 8]) = bh[i]; \
    }

    floatx4 acc[13];
#pragma unroll
    for (int c = 0; c < 13; ++c) acc[c] = (floatx4){0.f, 0.f, 0.f, 0.f};

    // consumer fragment base: w = (ks*4+q)*52 + c*4 + (n>>2), i = n&3
    const int rb16 = (n & 3) * BSTRIDE_I + q * 52 + (n >> 2);  // + ks*208 + c*4 + buf*BBUF

    // pipeline preamble: buf0 <- phase0 (rows 0-63); bh <- phase1
    LOAD_SLAB(0); CONV_SLAB(); WRITE_SLAB(0);
    LOAD_SLAB(1); CONV_SLAB();
    __syncthreads();

#pragma unroll
    for (int p = 0; p < 4; ++p) {
        if (p < 2) LOAD_SLAB(p + 2);           // loads in flight over MFMA + write
        if (wactive) {
            const int bb = (p & 1) * BBUF;
#pragma unroll
            for (int ks = 0; ks < 2; ++ks) {
                if (p * 64 + ks * 32 < ENT) {  // phase 3 ks=1 is all-pad: skip
#pragma unroll
                    for (int c = 0; c < 13; ++c) {
                        const short8 bf = *(const short8*)(&sB[(bb + rb16 + ks * 208 + c * 4) * 8]);
                        acc[c] = __builtin_amdgcn_mfma_f32_16x16x32_bf16(afrag[2 * p + ks], bf, acc[c], 0, 0, 0);
                    }
                }
            }
        }
        if (p < 3) WRITE_SLAB((p + 1) & 1);    // bh still holds phase p+1
        if (p < 2) CONV_SLAB();                // fm(p+2) -> bh
        if (p < 3) __syncthreads();
    }

    // ---- in-lane epilogue (active waves only) ----
    if (wactive) {
        float rl[13];
        const float* __restrict__ rb = rel_emb + (size_t)r * RELD;
#pragma unroll
        for (int c = 0; c < 13; ++c) {
            const int col = c * 16 + n;
            rl[c] = (col < RELD) ? rb[col] : 0.f;
        }
        float nsq[4] = {0.f, 0.f, 0.f, 0.f};
        float rsq = 0.f;
#pragma unroll
        for (int c = 0; c < 13; ++c) {
            nsq[0] += acc[c][0] * acc[c][0];
            nsq[1] += acc[c][1] * acc[c][1];
            nsq[2] += acc[c][2] * acc[c][2];
            nsq[3] += acc[c][3] * acc[c][3];
            rsq += rl[c] * rl[c];
        }
#pragma unroll
        for (int m = 1; m < 16; m <<= 1) {
#pragma unroll
            for (int k = 0; k < 4; ++k) nsq[k] += __shfl_xor(nsq[k], m, 64);
            rsq += __shfl_xor(rsq, m, 64);
        }
        float inv[4];
#pragma unroll
        for (int k = 0; k < 4; ++k) inv[k] = rsqrtf(fmaxf(nsq[k], 1e-12f));
        const float invr = rsqrtf(fmaxf(rsq, 1e-12f));

        float psum = 0.f, nsum = 0.f;
#pragma unroll
        for (int c = 0; c < 13; ++c) {
            const float rr = rl[c] * invr;
            psum += fabsf(acc[c][0] * inv[0] + rr - acc[c][1] * inv[1]);
            nsum += fabsf(acc[c][2] * inv[2] + rr - acc[c][3] * inv[3]);
        }
#pragma unroll
        for (int m = 1; m < 16; m <<= 1) {
            psum += __shfl_xor(psum, m, 64);
            nsum += __shfl_xor(nsum, m, 64);
        }
        const int item = wv * 4 + q;
        if (n == 0 && item < cnt) {
            float* elem = (float*)(ws + WS_ELEM);
            elem[items_s[item]] = fmaxf(psum - nsum + MARGIN, 0.f);
        }
    }
}

__global__ __launch_bounds__(256) void reduce_mean_kernel(const int* __restrict__ ws,
                                                          float* __restrict__ out) {
    __shared__ float sred[4];
    const float4* elem = (const float4*)(ws + WS_ELEM);
    float s = 0.f;
    for (int i = threadIdx.x; i < NBATCH / 4; i += 256) {
        const float4 v = elem[i];
        s += v.x + v.y + v.z + v.w;
    }
    s = wave_reduce(s);
    const int lane = threadIdx.x & 63;
    const int wvv = threadIdx.x >> 6;
    if (lane == 0) sred[wvv] = s;
    __syncthreads();
    if (threadIdx.x == 0)
        out[0] = (sred[0] + sred[1] + sred[2] + sred[3]) * (1.0f / (float)NBATCH);
}

extern "C" void kernel_launch(void* const* d_in, const int* in_sizes, int n_in,
                              void* d_out, int out_size, void* d_ws, size_t ws_size,
                              hipStream_t stream) {
    const int* pos_h = (const int*)d_in[0];
    const int* pos_t = (const int*)d_in[1];
    const int* pos_r = (const int*)d_in[2];
    const int* neg_h = (const int*)d_in[3];
    const int* neg_t = (const int*)d_in[4];
    const float* ent_emb = (const float*)d_in[5];
    const float* rel_emb = (const float*)d_in[6];
    const float* transfer = (const float*)d_in[7];

    int* ws = (int*)d_ws;
    float* out = (float*)d_out;

    prep_kernel<<<1, 1024, 0, stream>>>(pos_r, ws);
    transr_mfma_kernel<<<MAXCHUNKS, 512, 0, stream>>>(
        pos_h, pos_t, neg_h, neg_t, ent_emb, rel_emb, transfer, ws);
    reduce_mean_kernel<<<1, 256, 0, stream>>>(ws, out);
}